// Round 6
// baseline (875.632 us; speedup 1.0000x reference)
//
#include <hip/hip_runtime.h>
#include <math.h>
#include <stdint.h>

// ScalarSGC: 2 layers of  x <- elu( scalars[l] * (A @ x) )
// Build (zero global atomics): fused convert+coarse-count -> 3-phase scan ->
//   LDS-cursor partition -> per-bucket fine sort by (localrow, colslice)
//   emitting per-(row,slice) offsets.
// SpMM: de-facto persistent (all blocks co-resident), slice-outer loop so all
//   XCDs gather from one 4MB column slice at a time (L2-resident), register
//   accumulators per wave-owned row set, fused scale + ELU.

#define D_FEAT 128
#define D2     64
#define SCAN_TILE 1024

#define PB 256             // partition/count blocks
#define PT 1024            // threads per partition/count block
#define RB_BITS 8          // rows per bucket = 256
#define ROWS_PER_BUCKET 256
#define COL_BITS 17        // N = 100000 < 2^17
#define SLICE_BITS 3       // 8 column slices
#define NSLICE 8
#define SLICE_SHIFT 14     // slice = col >> 14  (16384 rows = 4MB bf16)
#define FINE_BINS (ROWS_PER_BUCKET << SLICE_BITS)   // 2048
#define CACHE_CAP 9216     // LDS edge cache (bucket mean 8184, +11 sigma)

#define SPMM_BLOCKS 1024
#define SPMM_WAVES  4096   // 1024 blocks * 4 waves
#define MAX_ROWS_PER_WAVE 25

__device__ __forceinline__ uint32_t f2bf(float f) {
    uint32_t u = __float_as_uint(f);
    return (u + 0x7FFFu + ((u >> 16) & 1u)) >> 16;   // RNE
}
__device__ __forceinline__ float bf_lo(uint32_t w) { return __uint_as_float(w << 16); }
__device__ __forceinline__ float bf_hi(uint32_t w) { return __uint_as_float(w & 0xFFFF0000u); }

// ---------- fused f32->bf16 convert + coarse per-(bucket,block) count ----------
__global__ __launch_bounds__(PT) void convert_count_kernel(
    const float2* __restrict__ xin, uint32_t* __restrict__ xbf, int n2,
    const int* __restrict__ row, int* __restrict__ cnt, int E, int nbuck) {
    __shared__ int hist[512];
    const int t = threadIdx.x;
    if (t < 512) hist[t] = 0;

    const int stride = PB * PT;
    for (int i = blockIdx.x * PT + t; i < n2; i += stride) {
        float2 f = xin[i];
        xbf[i] = f2bf(f.x) | (f2bf(f.y) << 16);
    }
    __syncthreads();
    for (int i = blockIdx.x * PT + t; i < E; i += stride)
        atomicAdd(&hist[row[i] >> RB_BITS], 1);
    __syncthreads();
    if (t < nbuck) cnt[t * PB + blockIdx.x] = hist[t];
}

// ---------------- scan phase 1: per-tile exclusive scan + tile sums ----------------
__global__ __launch_bounds__(SCAN_TILE) void scan1_kernel(const int* __restrict__ counts,
                                                          int* __restrict__ excl,
                                                          int* __restrict__ tileSums, int n) {
    __shared__ int wsum[16];
    const int tid  = threadIdx.x;
    const int lane = tid & 63;
    const int wave = tid >> 6;
    const int i    = blockIdx.x * SCAN_TILE + tid;

    int v = (i < n) ? counts[i] : 0;
    int incl = v;
    #pragma unroll
    for (int off = 1; off < 64; off <<= 1) {
        int t = __shfl_up(incl, off, 64);
        if (lane >= off) incl += t;
    }
    if (lane == 63) wsum[wave] = incl;
    __syncthreads();
    if (wave == 0) {
        int s = (lane < 16) ? wsum[lane] : 0;
        #pragma unroll
        for (int off = 1; off < 16; off <<= 1) {
            int t = __shfl_up(s, off, 64);
            if (lane >= off) s += t;
        }
        if (lane < 16) wsum[lane] = s;
    }
    __syncthreads();
    int wbase = (wave == 0) ? 0 : wsum[wave - 1];
    if (i < n) excl[i] = wbase + (incl - v);
    if (tid == 0) tileSums[blockIdx.x] = wsum[15];
}

// ---------------- scan phase 2: scan tile sums (single block) ----------------
__global__ __launch_bounds__(1024) void scan2_kernel(const int* __restrict__ tileSums,
                                                     int* __restrict__ tileBase,
                                                     int* __restrict__ total_out, int nb) {
    __shared__ int buf[1024];
    const int tid = threadIdx.x;
    int v = (tid < nb) ? tileSums[tid] : 0;
    buf[tid] = v;
    __syncthreads();
    #pragma unroll
    for (int off = 1; off < 1024; off <<= 1) {
        int t = (tid >= off) ? buf[tid - off] : 0;
        __syncthreads();
        buf[tid] += t;
        __syncthreads();
    }
    if (tid < nb) tileBase[tid] = buf[tid] - v;
    if (tid == nb - 1) *total_out = buf[tid];
}

// ---------------- partition edges into coarse buckets (LDS cursors) ------
__global__ __launch_bounds__(PT) void partition_kernel(const int* __restrict__ row,
                                                       const int* __restrict__ col,
                                                       const float* __restrict__ val,
                                                       const int* __restrict__ cnt,
                                                       const int* __restrict__ tileBase,
                                                       int2* __restrict__ pack2,
                                                       int E, int nbuck) {
    __shared__ int cur[512];
    const int t = threadIdx.x;
    if (t < nbuck) {
        int idx = t * PB + blockIdx.x;
        cur[t] = cnt[idx] + tileBase[idx >> 10];
    }
    __syncthreads();
    const int stride = PB * PT;
    for (int i = blockIdx.x * PT + t; i < E; i += stride) {
        int r = row[i];
        int pos = atomicAdd(&cur[r >> RB_BITS], 1);   // LDS atomic
        pack2[pos] = make_int2(col[i] | ((r & (ROWS_PER_BUCKET - 1)) << COL_BITS),
                               __float_as_int(val[i]));
    }
}

// ------ per-bucket fine sort by (localrow, colslice); emits offsets2 ------
__global__ __launch_bounds__(1024) void fine_sort_kernel(const int* __restrict__ cnt,
                                                         const int* __restrict__ tileBase,
                                                         const int2* __restrict__ pack2,
                                                         int2* __restrict__ pack,
                                                         int* __restrict__ offsets2,
                                                         int E, int nbuck) {
    __shared__ int2 ecache[CACHE_CAP];    // 72 KB
    __shared__ int  bins[FINE_BINS];      // 8 KB  (hist -> abs start -> cursor)
    __shared__ int  sbuf[1024];
    const int b = blockIdx.x;
    const int t = threadIdx.x;
    const int start = cnt[b << 8] + tileBase[b >> 2];
    const int end   = (b == nbuck - 1) ? E : (cnt[(b + 1) << 8] + tileBase[(b + 1) >> 2]);
    const int n  = end - start;
    const int nc = (n < CACHE_CAP) ? n : CACHE_CAP;

    for (int i = t; i < nc; i += 1024) ecache[i] = pack2[start + i];
    bins[t] = 0; bins[t + 1024] = 0;
    __syncthreads();

    for (int i = t; i < n; i += 1024) {
        int key = (i < nc) ? ecache[i].x : pack2[start + i].x;
        int bin = ((key >> COL_BITS) << SLICE_BITS) | ((key >> SLICE_SHIFT) & (NSLICE - 1));
        atomicAdd(&bins[bin], 1);
    }
    __syncthreads();

    // scan 2048 bins: thread t owns bins 2t, 2t+1
    int c0 = bins[2 * t], c1 = bins[2 * t + 1];
    int pair = c0 + c1;
    sbuf[t] = pair;
    __syncthreads();
    for (int off = 1; off < 1024; off <<= 1) {
        int tv = (t >= off) ? sbuf[t - off] : 0;
        __syncthreads();
        sbuf[t] += tv;
        __syncthreads();
    }
    int pexcl = sbuf[t] - pair;
    int a0 = start + pexcl, a1 = start + pexcl + c0;
    bins[2 * t]     = a0;
    bins[2 * t + 1] = a1;
    const int gbase = b << (RB_BITS + SLICE_BITS);
    offsets2[gbase + 2 * t]     = a0;
    offsets2[gbase + 2 * t + 1] = a1;
    if (b == 0 && t == 0) offsets2[nbuck << (RB_BITS + SLICE_BITS)] = E;
    __syncthreads();

    for (int i = t; i < n; i += 1024) {
        int2 w = (i < nc) ? ecache[i] : pack2[start + i];
        int bin = ((w.x >> COL_BITS) << SLICE_BITS) | ((w.x >> SLICE_SHIFT) & (NSLICE - 1));
        int p = atomicAdd(&bins[bin], 1);             // LDS atomic
        pack[p] = make_int2(w.x & ((1 << COL_BITS) - 1), w.y);
    }
}

// ------------- slice-phased persistent SpMM + scalar scale + ELU -------------
// 1024 blocks x 256 thr, all co-resident; wave owns <=25 contiguous rows with
// register accumulators; slice-outer loop keeps each 4MB column slice L2-hot.
template <int OUT_BF16>
__global__ __launch_bounds__(256, 4) void spmm_elu_kernel(
    const int* __restrict__ offs2, const int2* __restrict__ pack,
    const uint32_t* __restrict__ xin, void* __restrict__ xout,
    const float* __restrict__ scalars, int layer, int N) {
    const int wid  = blockIdx.x * 4 + (threadIdx.x >> 6);
    const uint32_t lane = threadIdx.x & 63;
    const int q   = N / SPMM_WAVES;            // 24
    const int rem = N - q * SPMM_WAVES;        // 1696
    const int base = wid * q + (wid < rem ? wid : rem);
    const int nr   = q + (wid < rem ? 1 : 0);  // 24 or 25

    float ax[MAX_ROWS_PER_WAVE], ay[MAX_ROWS_PER_WAVE];
    #pragma unroll
    for (int k = 0; k < MAX_ROWS_PER_WAVE; ++k) { ax[k] = 0.f; ay[k] = 0.f; }

    for (int s = 0; s < NSLICE; ++s) {
        #pragma unroll
        for (int k = 0; k < MAX_ROWS_PER_WAVE; ++k) {
            if (k >= nr) break;
            const int r = base + k;
            int e        = offs2[(r << SLICE_BITS) + s];
            const int e1 = offs2[(r << SLICE_BITS) + s + 1];
            float sx = 0.f, sy = 0.f;
            float tx = 0.f, ty = 0.f;
            for (; e + 2 <= e1; e += 2) {
                int2 p0 = pack[e], p1 = pack[e + 1];
                uint32_t w0 = xin[(((uint32_t)p0.x) << 6) + lane];
                uint32_t w1 = xin[(((uint32_t)p1.x) << 6) + lane];
                float v0 = __int_as_float(p0.y), v1 = __int_as_float(p1.y);
                sx += v0 * bf_lo(w0); sy += v0 * bf_hi(w0);
                tx += v1 * bf_lo(w1); ty += v1 * bf_hi(w1);
            }
            if (e < e1) {
                int2 p = pack[e];
                uint32_t w = xin[(((uint32_t)p.x) << 6) + lane];
                float v = __int_as_float(p.y);
                sx += v * bf_lo(w); sy += v * bf_hi(w);
            }
            ax[k] += sx + tx;
            ay[k] += sy + ty;
        }
    }

    const float sc = scalars[layer];
    #pragma unroll
    for (int k = 0; k < MAX_ROWS_PER_WAVE; ++k) {
        if (k >= nr) break;
        const int r = base + k;
        float vx = ax[k] * sc, vy = ay[k] * sc;
        vx = (vx > 0.f) ? vx : (expf(vx) - 1.f);
        vy = (vy > 0.f) ? vy : (expf(vy) - 1.f);
        if (OUT_BF16) {
            ((uint32_t*)xout)[((uint32_t)r << 6) + lane] = f2bf(vx) | (f2bf(vy) << 16);
        } else {
            ((float2*)xout)[((uint32_t)r << 6) + lane] = make_float2(vx, vy);
        }
    }
}

extern "C" void kernel_launch(void* const* d_in, const int* in_sizes, int n_in,
                              void* d_out, int out_size, void* d_ws, size_t ws_size,
                              hipStream_t stream) {
    const float* x         = (const float*)d_in[0];
    const int*   edge_row  = (const int*)d_in[1];
    const int*   edge_col  = (const int*)d_in[2];
    const float* edge_vals = (const float*)d_in[3];
    const float* scalars   = (const float*)d_in[4];

    const int N = in_sizes[0] / D_FEAT;                      // 100000
    const int E = in_sizes[1];                               // 3200000
    const int nbuck = (N + ROWS_PER_BUCKET - 1) >> RB_BITS;  // 391
    const int M = nbuck * PB;                                // 100096
    const int NB = (M + SCAN_TILE - 1) / SCAN_TILE;          // 98
    const int NOFF = (nbuck << (RB_BITS + SLICE_BITS)) + 1;  // offsets2 size

    // ---- workspace bump allocator (256B aligned) ----
    char*  ws  = (char*)d_ws;
    size_t off = 0;
    auto alloc = [&](size_t bytes) -> void* {
        off = (off + 255) & ~(size_t)255;
        void* p = ws + off;
        off += bytes;
        return p;
    };
    int*      offsets2 = (int*)alloc((size_t)NOFF * sizeof(int));
    int*      cnt      = (int*)alloc((size_t)(M + 1) * sizeof(int));
    int*      tileSums = (int*)alloc((size_t)NB * sizeof(int));
    int*      tileBase = (int*)alloc((size_t)NB * sizeof(int));
    int2*     pack2    = (int2*)alloc((size_t)E * sizeof(int2));
    int2*     pack     = (int2*)alloc((size_t)E * sizeof(int2));
    uint32_t* xbf      = (uint32_t*)alloc((size_t)N * D2 * sizeof(uint32_t));
    uint32_t* hbf      = (uint32_t*)pack2;   // alias: pack2 dead after fine_sort
    (void)ws_size;

    // ---- build: bf16 table + CSR(row,slice) with no global atomics ----
    convert_count_kernel<<<PB, PT, 0, stream>>>((const float2*)x, xbf, N * D2,
                                                edge_row, cnt, E, nbuck);
    scan1_kernel<<<NB, SCAN_TILE, 0, stream>>>(cnt, cnt, tileSums, M);
    scan2_kernel<<<1, 1024, 0, stream>>>(tileSums, tileBase, cnt + M, NB);
    partition_kernel<<<PB, PT, 0, stream>>>(edge_row, edge_col, edge_vals, cnt, tileBase,
                                            pack2, E, nbuck);
    fine_sort_kernel<<<nbuck, 1024, 0, stream>>>(cnt, tileBase, pack2, pack, offsets2,
                                                 E, nbuck);

    // ---- layer 1: xbf -> hbf (bf16), layer 2: hbf -> d_out (f32) ----
    spmm_elu_kernel<1><<<SPMM_BLOCKS, 256, 0, stream>>>(offsets2, pack, xbf, hbf,
                                                        scalars, 0, N);
    spmm_elu_kernel<0><<<SPMM_BLOCKS, 256, 0, stream>>>(offsets2, pack, hbf, (void*)d_out,
                                                        scalars, 1, N);
}